// Round 3
// 1045.698 us; speedup vs baseline: 1.0310x; 1.0310x over previous
//
#include <hip/hip_runtime.h>
#include <hip/hip_bf16.h>
#include <math.h>
#include <stdint.h>

#define E_   64
#define CAP_ 1024
#define D_   512
#define H_   2048

typedef short s8v __attribute__((ext_vector_type(8)));
typedef float f4v __attribute__((ext_vector_type(4)));

// fp32 -> bf16 round-to-nearest-even (no NaN concern for this data)
__device__ __forceinline__ short f2bf(float f) {
  unsigned u = __float_as_uint(f);
  u += 0x7fffu + ((u >> 16) & 1u);
  return (short)(u >> 16);
}

// async global->LDS, 16B per lane; lds dest = wave-uniform base + lane*16
__device__ __forceinline__ void gll16(const void* g, const void* l) {
  __builtin_amdgcn_global_load_lds(
      (__attribute__((address_space(1))) void*)(uintptr_t)g,
      (__attribute__((address_space(3))) void*)(uintptr_t)l, 16, 0, 0);
}

// -------- straight fp32 -> bf16 convert (x) --------
__global__ __launch_bounds__(256) void convk(const float* __restrict__ in,
                                             short* __restrict__ out, int n4) {
  int i = blockIdx.x * 256 + threadIdx.x;
  if (i >= n4) return;
  float4 v = ((const float4*)in)[i];
  short4 s;
  s.x = f2bf(v.x); s.y = f2bf(v.y); s.z = f2bf(v.z); s.w = f2bf(v.w);
  ((short4*)out)[i] = s;
}

// -------- transpose-convert: in[e][R][C] f32 -> out[e][C][R] bf16 --------
// grid (C/64, R/64, E), block 256. float4 global loads, short8 (16B) stores.
// LDS tile is written TRANSPOSED (t[col][row]) so the store phase reads
// contiguous runs. R1/R2 bug: tile was written row-major but read col-major.
__global__ __launch_bounds__(256) void tconvk(const float* __restrict__ in,
                                              short* __restrict__ out, int R, int C) {
  __shared__ float t[64][65];  // [col][row]; stride 65 -> <=2-way bank conflicts
  const int e = blockIdx.z;
  const int r0 = blockIdx.y * 64, c0 = blockIdx.x * 64;
  const float* pin = in + (size_t)e * R * C;
  short* pout = out + (size_t)e * R * C;
  const int tid = threadIdx.x;
#pragma unroll
  for (int i = 0; i < 4; i++) {
    int item = tid + i * 256;          // 1024 float4 = 64x64 tile
    int row  = item >> 4;
    int c4   = (item & 15) * 4;
    float4 v = *(const float4*)&pin[(size_t)(r0 + row) * C + c0 + c4];
    t[c4 + 0][row] = v.x;
    t[c4 + 1][row] = v.y;
    t[c4 + 2][row] = v.z;
    t[c4 + 3][row] = v.w;
  }
  __syncthreads();
#pragma unroll
  for (int i = 0; i < 2; i++) {
    int item = tid + i * 256;          // 512 short8 stores = 64x64 tile
    int rg   = item & 7;               // 8-row group along R
    int cc   = (item >> 3) & 63;       // output row (= input col)
    s8v s;
#pragma unroll
    for (int j = 0; j < 8; j++) s[j] = f2bf(t[cc][rg * 8 + j]);
    *(s8v*)&pout[(size_t)(c0 + cc) * R + r0 + rg * 8] = s;
  }
}

// -------- bf16 MFMA GEMM, 2-phase double-buffered, EXPLICIT sync --------
// A   : [E][M][K] bf16 row-major (k-contig)
// Bt  : [E][N][K] bf16 row-major (k-contig)  (i.e. B transposed)
// C = A*B (+bias), GEMM1: +GELU -> bf16 h; GEMM2: +mask -> fp32 y
// grid (N/128, M/128, E), block 256 (4 waves, each 64x64 = 4x4 16x16x32 frags)
template <int M, int N, int K, bool SECOND>
__global__ __launch_bounds__(256)
void ffn_gemm(const short* __restrict__ Aall, const short* __restrict__ Btall,
              const float* __restrict__ bias, const int* __restrict__ valid,
              short* __restrict__ hOut, float* __restrict__ yOut) {
  __shared__ __align__(16) short sA0[128 * 32];
  __shared__ __align__(16) short sB0[128 * 32];
  __shared__ __align__(16) short sA1[128 * 32];
  __shared__ __align__(16) short sB1[128 * 32];

  const int e   = blockIdx.z;
  const int m0  = blockIdx.y * 128;
  const int n0  = blockIdx.x * 128;
  const int vl  = valid[e];
  const int tid = threadIdx.x;
  const int l   = tid & 63;
  const int w   = tid >> 6;

  if (m0 >= vl) {
    // fully-masked row block: GEMM1 skips (h never read); GEMM2 zero-fills y
    if (SECOND) {
      float4 z = make_float4(0.f, 0.f, 0.f, 0.f);
      float* yb = yOut + (size_t)e * M * N;
      for (int i = tid; i < 128 * 128 / 4; i += 256) {
        int r = i >> 5, c4 = i & 31;
        *(float4*)&yb[(size_t)(m0 + r) * N + n0 + c4 * 4] = z;
      }
    }
    return;
  }

  const short* Ae = Aall  + (size_t)e * M * K;
  const short* Be = Btall + (size_t)e * N * K;

  // staging: wave w stages tile rows [w*32, w*32+32), 2 issues x 16 rows each side
  const int srow = w * 32 + (l >> 2);
  const int scol = (l & 3) * 8;
  const short* gA = Ae + (size_t)(m0 + srow) * K + scol;
  const short* gB = Be + (size_t)(n0 + srow) * K + scol;
  const int lofs = w * 32 * 32;  // wave-uniform LDS offset within a buffer

  const int wm = (w >> 1) * 64;   // wave's 64x64 sub-tile
  const int wn = (w & 1) * 64;
  const int fr = (l & 15) * 32 + (l >> 4) * 8;  // frag: row=lane&15, k=quad*8

  f4v acc[4][4];
#pragma unroll
  for (int a = 0; a < 4; a++)
#pragma unroll
    for (int b = 0; b < 4; b++)
      acc[a][b] = f4v{0.f, 0.f, 0.f, 0.f};

  const int KT = K / 32;
  static_assert((K / 32) % 2 == 0, "KT must be even for 2x-unrolled dbuf");

#define STAGE(SAb, SBb)                       \
  gll16(gA,          &SAb[lofs]);             \
  gll16(gA + 16 * K, &SAb[lofs + 16 * 32]);   \
  gll16(gB,          &SBb[lofs]);             \
  gll16(gB + 16 * K, &SBb[lofs + 16 * 32]);   \
  gA += 32; gB += 32;

#define COMPUTE(SAb, SBb)                                                   \
  {                                                                         \
    s8v af[4], bfr[4];                                                      \
    _Pragma("unroll")                                                       \
    for (int i = 0; i < 4; i++)                                             \
      af[i] = *(const s8v*)&SAb[(wm + i * 16) * 32 + fr];                   \
    _Pragma("unroll")                                                       \
    for (int i = 0; i < 4; i++)                                             \
      bfr[i] = *(const s8v*)&SBb[(wn + i * 16) * 32 + fr];                  \
    _Pragma("unroll")                                                       \
    for (int a = 0; a < 4; a++)                                             \
      _Pragma("unroll")                                                     \
      for (int b = 0; b < 4; b++)                                           \
        acc[a][b] = __builtin_amdgcn_mfma_f32_16x16x32_bf16(                \
            af[a], bfr[b], acc[a][b], 0, 0, 0);                             \
  }

#define SYNCB()                                                 \
  __builtin_amdgcn_sched_barrier(0);                            \
  asm volatile("s_waitcnt vmcnt(0) lgkmcnt(0)" ::: "memory");   \
  __builtin_amdgcn_s_barrier();                                 \
  __builtin_amdgcn_sched_barrier(0);

  // prologue: tile 0 -> buf0
  STAGE(sA0, sB0);
  SYNCB();

  for (int kt = 0; kt < KT; kt += 2) {
    // half A: prefetch tile kt+1 -> buf1 (issue pinned early), compute tile kt
    STAGE(sA1, sB1);
    __builtin_amdgcn_sched_barrier(0);
    COMPUTE(sA0, sB0);
    SYNCB();
    // half B: prefetch tile kt+2 -> buf0 (if any), compute tile kt+1
    if (kt + 2 < KT) {
      STAGE(sA0, sB0);
      __builtin_amdgcn_sched_barrier(0);
    }
    COMPUTE(sA1, sB1);
    SYNCB();
  }

#undef STAGE
#undef COMPUTE
#undef SYNCB

  // epilogue: C/D layout col=lane&15, row=quad*4+reg
  const int rbase = m0 + wm + (l >> 4) * 4;
  const int cbase = n0 + wn + (l & 15);
  const float* be = bias + (size_t)e * N;
  if (!SECOND) {
    short* hb = hOut + (size_t)e * M * N;
#pragma unroll
    for (int b = 0; b < 4; b++) {
      int col = cbase + b * 16;
      float bv = be[col];
#pragma unroll
      for (int a = 0; a < 4; a++) {
#pragma unroll
        for (int r = 0; r < 4; r++) {
          int row = rbase + a * 16 + r;
          float v = acc[a][b][r] + bv;
          v = v * 0.5f * (1.0f + erff(v * 0.70710678118f));  // exact-erf GELU
          hb[(size_t)row * N + col] = f2bf(v);
        }
      }
    }
  } else {
    float* yb = yOut + (size_t)e * M * N;
#pragma unroll
    for (int b = 0; b < 4; b++) {
      int col = cbase + b * 16;
      float bv = be[col];
#pragma unroll
      for (int a = 0; a < 4; a++) {
#pragma unroll
        for (int r = 0; r < 4; r++) {
          int row = rbase + a * 16 + r;
          float v = acc[a][b][r] + bv;
          yb[(size_t)row * N + col] = (row < vl) ? v : 0.0f;
        }
      }
    }
  }
}

extern "C" void kernel_launch(void* const* d_in, const int* in_sizes, int n_in,
                              void* d_out, int out_size, void* d_ws, size_t ws_size,
                              hipStream_t stream) {
  (void)in_sizes; (void)n_in; (void)out_size; (void)ws_size;
  const float* x  = (const float*)d_in[0];
  const int*   vl = (const int*)d_in[1];
  const float* w1 = (const float*)d_in[2];
  const float* b1 = (const float*)d_in[3];
  const float* w2 = (const float*)d_in[4];
  const float* b2 = (const float*)d_in[5];
  float* y = (float*)d_out;

  // workspace layout (bf16 shorts): x | w1^T | w2^T | h   = 604 MB total
  short* xb  = (short*)d_ws;
  short* w1t = xb  + (size_t)E_ * CAP_ * D_;   //  67.1 MB
  short* w2t = w1t + (size_t)E_ * D_ * H_;     // 134.2 MB
  short* hb  = w2t + (size_t)E_ * H_ * D_;     // 134.2 MB (h: 268.4 MB)

  // 1) x fp32 -> bf16
  int n4 = E_ * CAP_ * D_ / 4;
  convk<<<dim3(n4 / 256), dim3(256), 0, stream>>>(x, xb, n4);
  // 2) w1 [E][D][H] -> w1t [E][H][D] bf16
  tconvk<<<dim3(H_ / 64, D_ / 64, E_), dim3(256), 0, stream>>>(w1, w1t, D_, H_);
  // 3) w2 [E][H][D] -> w2t [E][D][H] bf16
  tconvk<<<dim3(D_ / 64, H_ / 64, E_), dim3(256), 0, stream>>>(w2, w2t, H_, D_);
  // 4) h = gelu(x @ w1 + b1)   [E][CAP][H] bf16
  hipLaunchKernelGGL((ffn_gemm<CAP_, H_, D_, false>),
                     dim3(H_ / 128, CAP_ / 128, E_), dim3(256), 0, stream,
                     xb, w1t, b1, vl, hb, (float*)nullptr);
  // 5) y = mask(h @ w2 + b2)   [E][CAP][D] fp32
  hipLaunchKernelGGL((ffn_gemm<CAP_, D_, H_, true>),
                     dim3(D_ / 128, CAP_ / 128, E_), dim3(256), 0, stream,
                     hb, w2t, b2, vl, (short*)nullptr, y);
}